// Round 7
// baseline (7967.187 us; speedup 1.0000x reference)
//
#include <hip/hip_runtime.h>
#include <math.h>

#define NPTS  2048
#define DIM   96
#define PITCH 2048
#define TB    8
#define NBLK  192
#define NTHR  512
#define TAIL  192

// ---- fixed-slot state: slot index == cluster representative (min point) ----
__device__ double g_cent[DIM * PITCH];   // transposed centroids, in-place updates
__device__ double g_sz[NPTS];
__device__ double g_nrm[NPTS];
__device__ int    g_act[NPTS];
__device__ double g_nnv[NPTS];
__device__ int    g_nni[NPTS];
__device__ int    g_reci[NPTS];          // merge records
__device__ int    g_recj[NPTS];
__device__ double g_rech[NPTS];
__device__ int    g_mcount;
__device__ int    g_barcnt = 0;          // spin-barrier state (self-restoring)
__device__ int    g_bargen = 0;

// Sense-reversing grid barrier. Safe: grid (192 blocks) is always co-resident
// (192 <= 256 CUs even at 1 block/CU). Device-scope atomics + threadfence give
// cross-XCD visibility of ordinary stores.
__device__ __forceinline__ void gridbar() {
    __syncthreads();
    if (threadIdx.x == 0) {
        __threadfence();
        int gen = __hip_atomic_load(&g_bargen, __ATOMIC_RELAXED, __HIP_MEMORY_SCOPE_AGENT);
        int prev = __hip_atomic_fetch_add(&g_barcnt, 1, __ATOMIC_ACQ_REL, __HIP_MEMORY_SCOPE_AGENT);
        if (prev == NBLK - 1) {
            __hip_atomic_store(&g_barcnt, 0, __ATOMIC_RELAXED, __HIP_MEMORY_SCOPE_AGENT);
            __hip_atomic_store(&g_bargen, gen + 1, __ATOMIC_RELEASE, __HIP_MEMORY_SCOPE_AGENT);
        } else {
            while (__hip_atomic_load(&g_bargen, __ATOMIC_ACQUIRE, __HIP_MEMORY_SCOPE_AGENT) == gen)
                __builtin_amdgcn_s_sleep(2);
        }
        __threadfence();
    }
    __syncthreads();
}

// Per-block order-preserving compaction of g_act -> sCidx; returns active count.
// All blocks compute identical results (deterministic), so no cross-block sync.
__device__ __forceinline__ int block_compact(unsigned short* sCidx, int* sWS) {
    const int t = threadIdx.x, lane = t & 63, w = t >> 6;
    int base = t * 4;
    int c0 = g_act[base], c1 = g_act[base + 1], c2 = g_act[base + 2], c3 = g_act[base + 3];
    int sum = c0 + c1 + c2 + c3;
    int v = sum;
#pragma unroll
    for (int off = 1; off < 64; off <<= 1) {
        int o = __shfl_up(v, off);
        if (lane >= off) v += o;
    }
    if (lane == 63) sWS[w] = v;
    __syncthreads();
    if (t == 0) {
        int run = 0;
#pragma unroll
        for (int i = 0; i < 8; ++i) { int x = sWS[i]; sWS[i] = run; run += x; }
        sWS[8] = run;
    }
    __syncthreads();
    int ex = sWS[w] + (v - sum);
    if (c0) sCidx[ex] = (unsigned short)base;       ex += c0;
    if (c1) sCidx[ex] = (unsigned short)(base + 1); ex += c1;
    if (c2) sCidx[ex] = (unsigned short)(base + 2); ex += c2;
    if (c3) sCidx[ex] = (unsigned short)(base + 3); ex += c3;
    int a = sWS[8];
    __syncthreads();
    return a;
}

// Wave-cooperative merge of mutual pair (b keeps, j dies): lanes over dims.
__device__ __forceinline__ void wave_merge(int b, int j, double hgt, int lane) {
    double sb = g_sz[b], sj = g_sz[j], s2 = sb + sj;
    int d0 = lane;
    double v0 = (sb * g_cent[d0 * PITCH + b] + sj * g_cent[d0 * PITCH + j]) / s2;
    g_cent[d0 * PITCH + b] = v0;
    double v1 = 0.0;
    if (lane < DIM - 64) {
        int d1 = lane + 64;
        v1 = (sb * g_cent[d1 * PITCH + b] + sj * g_cent[d1 * PITCH + j]) / s2;
        g_cent[d1 * PITCH + b] = v1;
    }
    double pnr = v0 * v0 + v1 * v1;
#pragma unroll
    for (int off = 1; off < 64; off <<= 1)
        pnr += __shfl_xor(pnr, off);
    if (lane == 0) {
        g_sz[b] = s2; g_nrm[b] = pnr; g_act[j] = 0;
        int r = atomicAdd(&g_mcount, 1);
        g_reci[r] = b; g_recj[r] = j; g_rech[r] = hgt;
    }
}

__global__ void __launch_bounds__(NTHR) fused(const float* __restrict__ x,
                                              const int* __restrict__ kptr,
                                              float* __restrict__ out, int out_size) {
    __shared__ unsigned short sCidx[NPTS];     //  4 KB compacted active list
    __shared__ double sMu[TB * DIM];           //  6 KB nn row tile
    __shared__ double sNb[TB], sSb[TB];
    __shared__ int    sIdx[TB];
    __shared__ double sRedV[64];
    __shared__ int    sRedI[64];
    __shared__ int    sPair[128];
    __shared__ int    sNp;
    __shared__ int    sWS[16];
    __shared__ double fD0[NPTS];               // 16 KB tail nnv / sort keys
    __shared__ int    fI0[NPTS];               //  8 KB tail nni / sort payload
    __shared__ int    fI1[NPTS];               //  8 KB parent ping
    __shared__ int    fI2[NPTS];               //  8 KB parent pong
    __shared__ int    fI3[NPTS];               //  8 KB rank ping
    __shared__ int    fI4[NPTS];               //  8 KB rank pong

    const int bid = blockIdx.x, t = threadIdx.x, lane = t & 63, w = t >> 6;

    // ---------------------------- init ------------------------------------
    for (int i = bid * NTHR + t; i < out_size; i += NBLK * NTHR) out[i] = 0.0f;
    for (int p = bid * NTHR + t; p < NPTS; p += NBLK * NTHR) {
        double nr = 0.0;
        for (int d = 0; d < DIM; ++d) {
            double v = (double)x[p * DIM + d];
            g_cent[d * PITCH + p] = v;
            nr += v * v;
        }
        g_nrm[p] = nr; g_sz[p] = 1.0; g_act[p] = 1;
    }
    if (bid == 0 && t == 0) g_mcount = 0;
    gridbar();

    int a = block_compact(sCidx, sWS);

    // ---------------------- grid-parallel MNN rounds ----------------------
    while (a > TAIL) {
        // nn over my tiles (identical arithmetic & tie-breaks to R6 nn_pass)
        for (int tile0 = bid * TB; tile0 < a; tile0 += NBLK * TB) {
            __syncthreads();
            if (t < TB) {
                int cm = tile0 + t;
                int orig = (cm < a) ? (int)sCidx[cm] : -1;
                sIdx[t] = orig;
                sNb[t] = (orig >= 0) ? g_nrm[orig] : 0.0;
                sSb[t] = (orig >= 0) ? g_sz[orig] : 1.0;
            }
            __syncthreads();
            for (int e = t; e < DIM * TB; e += NTHR) {
                int col = sIdx[e & 7];
                sMu[e] = (col >= 0) ? g_cent[(e >> 3) * PITCH + col] : 0.0;
            }
            __syncthreads();

            int om[4]; bool vld[4];
#pragma unroll
            for (int q = 0; q < 4; ++q) {
                int m = t + q * NTHR;
                vld[q] = (m < a);
                om[q] = (int)sCidx[vld[q] ? m : (a - 1)];
            }
            double acc[4][TB];
#pragma unroll
            for (int q = 0; q < 4; ++q)
#pragma unroll
                for (int bi = 0; bi < TB; ++bi) acc[q][bi] = 0.0;

            for (int d = 0; d < DIM; ++d) {
                double mu[TB];
#pragma unroll
                for (int bi = 0; bi < TB; ++bi) mu[bi] = sMu[d * TB + bi];
                double x0 = g_cent[d * PITCH + om[0]];
                double x1 = g_cent[d * PITCH + om[1]];
                double x2 = g_cent[d * PITCH + om[2]];
                double x3 = g_cent[d * PITCH + om[3]];
#pragma unroll
                for (int bi = 0; bi < TB; ++bi) {
                    acc[0][bi] += mu[bi] * x0;
                    acc[1][bi] += mu[bi] * x1;
                    acc[2][bi] += mu[bi] * x2;
                    acc[3][bi] += mu[bi] * x3;
                }
            }

            double bv[TB]; int bidx[TB];
#pragma unroll
            for (int bi = 0; bi < TB; ++bi) { bv[bi] = (double)INFINITY; bidx[bi] = 0x7FFFFFFF; }
#pragma unroll
            for (int q = 0; q < 4; ++q) {
                if (!vld[q]) continue;
                int cm = t + q * NTHR;
                double sm = g_sz[om[q]], nm = g_nrm[om[q]];
#pragma unroll
                for (int bi = 0; bi < TB; ++bi) {
                    double f = (sSb[bi] * sm) / (sSb[bi] + sm);
                    double D = (2.0 * f) * ((sNb[bi] + nm) - 2.0 * acc[q][bi]);
                    if (cm != tile0 + bi && D < bv[bi]) { bv[bi] = D; bidx[bi] = om[q]; }
                }
            }
#pragma unroll
            for (int bi = 0; bi < TB; ++bi) {
                double v = bv[bi]; int ix = bidx[bi];
                for (int off = 1; off < 64; off <<= 1) {
                    double ov = __shfl_xor(v, off);
                    int    oi = __shfl_xor(ix, off);
                    if (ov < v || (ov == v && oi < ix)) { v = ov; ix = oi; }
                }
                if (lane == 0) { sRedV[w * TB + bi] = v; sRedI[w * TB + bi] = ix; }
            }
            __syncthreads();
            if (t < TB && tile0 + t < a) {
                double v = sRedV[t]; int ix = sRedI[t];
                for (int w2 = 1; w2 < 8; ++w2) {
                    double ov = sRedV[w2 * TB + t]; int oi = sRedI[w2 * TB + t];
                    if (ov < v || (ov == v && oi < ix)) { v = ov; ix = oi; }
                }
                g_nnv[sIdx[t]] = v;
                g_nni[sIdx[t]] = ix;
            }
        }
        gridbar();

        // merge phase: detect my tiles' mutual pairs, wave-per-pair merge
        if (t == 0) sNp = 0;
        __syncthreads();
        for (int tile0 = bid * TB; tile0 < a; tile0 += NBLK * TB) {
            int cm = tile0 + t;
            if (t < TB && cm < a) {
                int b = (int)sCidx[cm];
                int j = g_nni[b];
                if (j > b && g_nni[j] == b) {
                    int s = atomicAdd(&sNp, 1);
                    sPair[s] = (b << 16) | j;
                }
            }
        }
        __syncthreads();
        int np = sNp;
        for (int p = w; p < np; p += 8) {
            int pk = sPair[p], b = pk >> 16, jj = pk & 0xFFFF;
            wave_merge(b, jj, g_nnv[b], lane);
        }
        gridbar();
        a = block_compact(sCidx, sWS);
    }

    if (bid != 0) return;

    // ------------------- single-block tail to full dendrogram -------------
    while (a > 1) {
        for (int c = w; c < a; c += 8) {              // wave per compacted row
            int b = (int)sCidx[c];
            double sb = g_sz[b], nb = g_nrm[b];
            double bv = (double)INFINITY; int bi2 = 0x7FFFFFFF;
            for (int cm = lane; cm < a; cm += 64) {
                int m = (int)sCidx[cm];
                if (m == b) continue;
                double dot = 0.0;
                for (int d = 0; d < DIM; ++d)
                    dot += g_cent[d * PITCH + b] * g_cent[d * PITCH + m];
                double sm = g_sz[m], nm = g_nrm[m];
                double f = (sb * sm) / (sb + sm);
                double D = (2.0 * f) * ((nb + nm) - 2.0 * dot);
                if (D < bv || (D == bv && m < bi2)) { bv = D; bi2 = m; }
            }
#pragma unroll
            for (int off = 1; off < 64; off <<= 1) {
                double ov = __shfl_xor(bv, off);
                int    oi = __shfl_xor(bi2, off);
                if (ov < bv || (ov == bv && oi < bi2)) { bv = ov; bi2 = oi; }
            }
            if (lane == 0) { fD0[b] = bv; fI0[b] = bi2; }
        }
        __syncthreads();
        if (t == 0) sNp = 0;
        __syncthreads();
        for (int c = t; c < a; c += NTHR) {
            int b = (int)sCidx[c];
            int j = fI0[b];
            if (j > b && fI0[j] == b) {
                int s = atomicAdd(&sNp, 1);
                sPair[s] = (b << 16) | j;
            }
        }
        __syncthreads();
        int np = sNp;
        for (int p = w; p < np; p += 8) {
            int pk = sPair[p], b = pk >> 16, jj = pk & 0xFFFF;
            wave_merge(b, jj, fD0[b], lane);
        }
        __syncthreads();
        a = block_compact(sCidx, sWS);
    }

    // ---- phase 3: sort heights, apply n-k smallest, rank roots, scatter ----
    const int k = *kptr;
    const int M = g_mcount;
    const int nsel = NPTS - k;
    __syncthreads();
    for (int e = t; e < NPTS; e += NTHR) {
        fD0[e] = (e < M) ? g_rech[e] : (double)INFINITY;
        fI0[e] = e;
    }
    __syncthreads();
    for (int k2 = 2; k2 <= NPTS; k2 <<= 1) {
        for (int j2 = k2 >> 1; j2 > 0; j2 >>= 1) {
            for (int i = t; i < NPTS; i += NTHR) {
                int ixj = i ^ j2;
                if (ixj > i) {
                    bool up = ((i & k2) == 0);
                    double a0 = fD0[i], a1 = fD0[ixj];
                    if (up ? (a0 > a1) : (a0 < a1)) {
                        fD0[i] = a1; fD0[ixj] = a0;
                        int ti_ = fI0[i]; fI0[i] = fI0[ixj]; fI0[ixj] = ti_;
                    }
                }
            }
            __syncthreads();
        }
    }
    for (int p = t; p < NPTS; p += NTHR) fI1[p] = p;
    __syncthreads();
    for (int r = t; r < nsel; r += NTHR) {
        int rec = fI0[r];
        fI1[g_recj[rec]] = g_reci[rec];   // each killed slot appears exactly once
    }
    __syncthreads();
    int* psrc = fI1; int* pdst = fI2;
    for (int it2 = 0; it2 < 11; ++it2) {          // 2^11 >= max chain depth
        for (int p = t; p < NPTS; p += NTHR) pdst[p] = psrc[psrc[p]];
        __syncthreads();
        int* tp = psrc; psrc = pdst; pdst = tp;
    }
    for (int p = t; p < NPTS; p += NTHR) fI3[p] = (psrc[p] == p) ? 1 : 0;
    __syncthreads();
    int* rsrc = fI3; int* rdst = fI4;
    for (int off = 1; off < NPTS; off <<= 1) {
        for (int p = t; p < NPTS; p += NTHR)
            rdst[p] = rsrc[p] + ((p >= off) ? rsrc[p - off] : 0);
        __syncthreads();
        int* tp = rsrc; rsrc = rdst; rdst = tp;
    }
    for (int p = t; p < NPTS; p += NTHR) {
        int lbl = rsrc[psrc[p]] - 1;              // rank of root, ascending
        out[(size_t)p * k + lbl] = 1.0f;
    }
}

// -------------------------------------------------------------- launch ----
extern "C" void kernel_launch(void* const* d_in, const int* in_sizes, int n_in,
                              void* d_out, int out_size, void* d_ws, size_t ws_size,
                              hipStream_t stream) {
    const float* x    = (const float*)d_in[0];
    const int*   kptr = (const int*)d_in[1];
    float*       out  = (float*)d_out;

    fused<<<NBLK, NTHR, 0, stream>>>(x, kptr, out, out_size);
}

// Round 8
// 3485.250 us; speedup vs baseline: 2.2860x; 2.2860x over previous
//
#include <hip/hip_runtime.h>
#include <math.h>

#define NPTS   2048
#define DIM    96
#define PITCH  2048
#define TB     8
#define NBLK   64
#define NTHR   512
#define TAILSZ 128
#define TPAD   130

// ---- fixed-slot state: slot index == cluster representative (min point) ----
__device__ double g_cent[DIM * PITCH];   // transposed centroids, in-place updates
__device__ double g_sz[NPTS];
__device__ double g_nrm[NPTS];
__device__ int    g_act[NPTS];
__device__ double g_nnv[NPTS];
__device__ int    g_nni[NPTS];
__device__ int    g_reci[NPTS];          // merge records
__device__ int    g_recj[NPTS];
__device__ double g_rech[NPTS];
__device__ int    g_mcount;
__device__ __attribute__((aligned(256))) int g_barcnt = 0;  // self-restoring
__device__ __attribute__((aligned(256))) int g_bargen = 0;  // generation counter

// Grid barrier: RELAXED spin (no per-probe acquire-invalidate storms);
// ordering via one release-fence before arrive + one acquire-fence after exit.
// Safe: 64 blocks @ ~115KB LDS = 1/CU, always co-resident on 256 CUs.
__device__ __forceinline__ void gridbar() {
    __syncthreads();
    if (threadIdx.x == 0) {
        __threadfence();   // release: write back this block's stores
        int gen  = __hip_atomic_load(&g_bargen, __ATOMIC_RELAXED, __HIP_MEMORY_SCOPE_AGENT);
        int prev = __hip_atomic_fetch_add(&g_barcnt, 1, __ATOMIC_RELAXED, __HIP_MEMORY_SCOPE_AGENT);
        if (prev == NBLK - 1) {
            __hip_atomic_store(&g_barcnt, 0, __ATOMIC_RELAXED, __HIP_MEMORY_SCOPE_AGENT);
            __hip_atomic_store(&g_bargen, gen + 1, __ATOMIC_RELAXED, __HIP_MEMORY_SCOPE_AGENT);
        } else {
            while (__hip_atomic_load(&g_bargen, __ATOMIC_RELAXED, __HIP_MEMORY_SCOPE_AGENT) == gen)
                __builtin_amdgcn_s_sleep(16);
        }
        __threadfence();   // acquire: invalidate stale lines before reading others'
    }
    __syncthreads();
}

// Per-block order-preserving compaction of g_act -> sCidx; returns active count.
// All blocks compute identical results from the same post-barrier snapshot.
__device__ __forceinline__ int block_compact(unsigned short* sCidx, int* sWS) {
    const int t = threadIdx.x, lane = t & 63, w = t >> 6;
    int base = t * 4;
    int c0 = g_act[base], c1 = g_act[base + 1], c2 = g_act[base + 2], c3 = g_act[base + 3];
    int sum = c0 + c1 + c2 + c3;
    int v = sum;
#pragma unroll
    for (int off = 1; off < 64; off <<= 1) {
        int o = __shfl_up(v, off);
        if (lane >= off) v += o;
    }
    if (lane == 63) sWS[w] = v;
    __syncthreads();
    if (t == 0) {
        int run = 0;
#pragma unroll
        for (int i = 0; i < 8; ++i) { int x = sWS[i]; sWS[i] = run; run += x; }
        sWS[8] = run;
    }
    __syncthreads();
    int ex = sWS[w] + (v - sum);
    if (c0) sCidx[ex] = (unsigned short)base;       ex += c0;
    if (c1) sCidx[ex] = (unsigned short)(base + 1); ex += c1;
    if (c2) sCidx[ex] = (unsigned short)(base + 2); ex += c2;
    if (c3) sCidx[ex] = (unsigned short)(base + 3); ex += c3;
    int a = sWS[8];
    __syncthreads();
    return a;
}

// Wave-cooperative merge of mutual pair (b keeps, j dies): lanes over dims.
__device__ __forceinline__ void wave_merge(int b, int j, double hgt, int lane) {
    double sb = g_sz[b], sj = g_sz[j], s2 = sb + sj;
    double v0 = (sb * g_cent[lane * PITCH + b] + sj * g_cent[lane * PITCH + j]) / s2;
    g_cent[lane * PITCH + b] = v0;
    double v1 = 0.0;
    if (lane < DIM - 64) {
        int d1 = lane + 64;
        v1 = (sb * g_cent[d1 * PITCH + b] + sj * g_cent[d1 * PITCH + j]) / s2;
        g_cent[d1 * PITCH + b] = v1;
    }
    double pnr = v0 * v0 + v1 * v1;
#pragma unroll
    for (int off = 1; off < 64; off <<= 1)
        pnr += __shfl_xor(pnr, off);
    if (lane == 0) {
        g_sz[b] = s2; g_nrm[b] = pnr; g_act[j] = 0;
        int r = atomicAdd(&g_mcount, 1);
        g_reci[r] = b; g_recj[r] = j; g_rech[r] = hgt;
    }
}

__global__ void __launch_bounds__(NTHR) fused(const float* __restrict__ x,
                                              const int* __restrict__ kptr,
                                              float* __restrict__ out, int out_size) {
    __shared__ unsigned short sCidx[NPTS];     //   4 KB compacted active list
    __shared__ double sMu[TB * DIM];           //   6 KB nn row tile
    __shared__ double sNb[TB], sSb[TB];
    __shared__ int    sIdx[TB];
    __shared__ double sRedV[64];
    __shared__ int    sRedI[64];
    __shared__ int    sPair[128];
    __shared__ int    sNp;
    __shared__ int    sWS[16];
    __shared__ double tCent[DIM * TPAD];       // 97.5 KB tail centroids / ph3 overlay
    __shared__ double tSz[TAILSZ], tNr[TAILSZ], tNNv[TAILSZ];
    __shared__ int    tNNi[TAILSZ], tCid[TAILSZ];
    __shared__ unsigned char tAct[TAILSZ];

    const int bid = blockIdx.x, t = threadIdx.x, lane = t & 63, w = t >> 6;

    // ---------------------------- init ------------------------------------
    for (int i = bid * NTHR + t; i < out_size; i += NBLK * NTHR) out[i] = 0.0f;
    for (int p = bid * NTHR + t; p < NPTS; p += NBLK * NTHR) {
        double nr = 0.0;
        for (int d = 0; d < DIM; ++d) {
            double v = (double)x[p * DIM + d];
            g_cent[d * PITCH + p] = v;
            nr += v * v;
        }
        g_nrm[p] = nr; g_sz[p] = 1.0; g_act[p] = 1;
    }
    if (bid == 0 && t == 0) g_mcount = 0;
    gridbar();

    int a = block_compact(sCidx, sWS);

    // ---------------------- grid-parallel MNN rounds ----------------------
    while (a > TAILSZ) {
        for (int tile0 = bid * TB; tile0 < a; tile0 += NBLK * TB) {
            __syncthreads();
            if (t < TB) {
                int cm = tile0 + t;
                int orig = (cm < a) ? (int)sCidx[cm] : -1;
                sIdx[t] = orig;
                sNb[t] = (orig >= 0) ? g_nrm[orig] : 0.0;
                sSb[t] = (orig >= 0) ? g_sz[orig] : 1.0;
            }
            __syncthreads();
            for (int e = t; e < DIM * TB; e += NTHR) {
                int col = sIdx[e & 7];
                sMu[e] = (col >= 0) ? g_cent[(e >> 3) * PITCH + col] : 0.0;
            }
            __syncthreads();

            int om[4]; bool vld[4];
#pragma unroll
            for (int q = 0; q < 4; ++q) {
                int m = t + q * NTHR;
                vld[q] = (m < a);
                om[q] = (int)sCidx[vld[q] ? m : (a - 1)];
            }
            double acc[4][TB];
#pragma unroll
            for (int q = 0; q < 4; ++q)
#pragma unroll
                for (int bi = 0; bi < TB; ++bi) acc[q][bi] = 0.0;

            for (int d = 0; d < DIM; ++d) {
                double mu[TB];
#pragma unroll
                for (int bi = 0; bi < TB; ++bi) mu[bi] = sMu[d * TB + bi];
                double x0 = g_cent[d * PITCH + om[0]];
                double x1 = g_cent[d * PITCH + om[1]];
                double x2 = g_cent[d * PITCH + om[2]];
                double x3 = g_cent[d * PITCH + om[3]];
#pragma unroll
                for (int bi = 0; bi < TB; ++bi) {
                    acc[0][bi] += mu[bi] * x0;
                    acc[1][bi] += mu[bi] * x1;
                    acc[2][bi] += mu[bi] * x2;
                    acc[3][bi] += mu[bi] * x3;
                }
            }

            double bv[TB]; int bidx[TB];
#pragma unroll
            for (int bi = 0; bi < TB; ++bi) { bv[bi] = (double)INFINITY; bidx[bi] = 0x7FFFFFFF; }
#pragma unroll
            for (int q = 0; q < 4; ++q) {
                if (!vld[q]) continue;
                int cm = t + q * NTHR;
                double sm = g_sz[om[q]], nm = g_nrm[om[q]];
#pragma unroll
                for (int bi = 0; bi < TB; ++bi) {
                    double f = (sSb[bi] * sm) / (sSb[bi] + sm);
                    double D = (2.0 * f) * ((sNb[bi] + nm) - 2.0 * acc[q][bi]);
                    if (cm != tile0 + bi && D < bv[bi]) { bv[bi] = D; bidx[bi] = om[q]; }
                }
            }
#pragma unroll
            for (int bi = 0; bi < TB; ++bi) {
                double v = bv[bi]; int ix = bidx[bi];
                for (int off = 1; off < 64; off <<= 1) {
                    double ov = __shfl_xor(v, off);
                    int    oi = __shfl_xor(ix, off);
                    if (ov < v || (ov == v && oi < ix)) { v = ov; ix = oi; }
                }
                if (lane == 0) { sRedV[w * TB + bi] = v; sRedI[w * TB + bi] = ix; }
            }
            __syncthreads();
            if (t < TB && tile0 + t < a) {
                double v = sRedV[t]; int ix = sRedI[t];
                for (int w2 = 1; w2 < 8; ++w2) {
                    double ov = sRedV[w2 * TB + t]; int oi = sRedI[w2 * TB + t];
                    if (ov < v || (ov == v && oi < ix)) { v = ov; ix = oi; }
                }
                g_nnv[sIdx[t]] = v;
                g_nni[sIdx[t]] = ix;
            }
        }
        gridbar();

        // merge phase: detect my tiles' mutual pairs, wave-per-pair merge
        if (t == 0) sNp = 0;
        __syncthreads();
        for (int tile0 = bid * TB; tile0 < a; tile0 += NBLK * TB) {
            int cm = tile0 + t;
            if (t < TB && cm < a) {
                int b = (int)sCidx[cm];
                int j = g_nni[b];
                if (j > b && g_nni[j] == b) {
                    int s = atomicAdd(&sNp, 1);
                    sPair[s] = (b << 16) | j;
                }
            }
        }
        __syncthreads();
        int np = sNp;
        for (int p = w; p < np; p += 8) {
            int pk = sPair[p], b = pk >> 16, jj = pk & 0xFFFF;
            wave_merge(b, jj, g_nnv[b], lane);
        }
        gridbar();
        a = block_compact(sCidx, sWS);
    }

    if (bid != 0) return;

    // ------------- single-block LDS-resident tail to full dendrogram ------
    const int a0 = a;
    for (int e = t; e < DIM * TAILSZ; e += NTHR) {
        int d = e >> 7, p = e & (TAILSZ - 1);
        tCent[d * TPAD + p] = (p < a0) ? g_cent[d * PITCH + (int)sCidx[p]] : 0.0;
    }
    if (t < TAILSZ) {
        bool vv = (t < a0);
        tSz[t]  = vv ? g_sz[(int)sCidx[t]]  : 1.0;
        tNr[t]  = vv ? g_nrm[(int)sCidx[t]] : 0.0;
        tCid[t] = vv ? (int)sCidx[t] : 0;
        tAct[t] = vv ? 1 : 0;
    }
    __syncthreads();

    while (a > 1) {
        // nn: thread t owns row t (positions ascending == original ids ascending)
        if (t < TAILSZ && tAct[t]) {
            double sb = tSz[t], nb = tNr[t];
            double bv = (double)INFINITY; int bi = 0x7FFFFFFF;
            for (int m = 0; m < TAILSZ; ++m) {
                if (!tAct[m]) continue;                 // uniform branch
                double d0 = 0.0, d1 = 0.0, d2 = 0.0, d3 = 0.0;
#pragma unroll
                for (int d = 0; d < DIM; d += 4) {      // 4-way split, bit-symmetric
                    d0 += tCent[(d    ) * TPAD + t] * tCent[(d    ) * TPAD + m];
                    d1 += tCent[(d + 1) * TPAD + t] * tCent[(d + 1) * TPAD + m];
                    d2 += tCent[(d + 2) * TPAD + t] * tCent[(d + 2) * TPAD + m];
                    d3 += tCent[(d + 3) * TPAD + t] * tCent[(d + 3) * TPAD + m];
                }
                double dot = (d0 + d1) + (d2 + d3);
                double sm = tSz[m];
                double f = (sb * sm) / (sb + sm);
                double D = (2.0 * f) * ((nb + tNr[m]) - 2.0 * dot);
                if (m != t && D < bv) { bv = D; bi = m; }   // ascending m: smallest id tie-break
            }
            tNNv[t] = bv; tNNi[t] = bi;
        }
        __syncthreads();
        if (t == 0) sNp = 0;
        __syncthreads();
        if (t < TAILSZ && tAct[t]) {
            int j = tNNi[t];
            if (j > t && j < TAILSZ && tNNi[j] == t) {     // mutual, t = keeper
                double sb = tSz[t], sj = tSz[j], s2 = sb + sj;
                double nr = 0.0;
                for (int d = 0; d < DIM; ++d) {
                    double v = (sb * tCent[d * TPAD + t] + sj * tCent[d * TPAD + j]) / s2;
                    tCent[d * TPAD + t] = v;
                    nr += v * v;
                }
                tSz[t] = s2; tNr[t] = nr;
                tAct[j] = 0;
                int r = atomicAdd(&g_mcount, 1);
                g_reci[r] = tCid[t]; g_recj[r] = tCid[j]; g_rech[r] = tNNv[t];
                atomicAdd(&sNp, 1);
            }
        }
        __syncthreads();
        a -= sNp;
        __syncthreads();
    }

    // ---- phase 3: sort heights, apply n-k smallest, rank roots, scatter ----
    double* fD0 = tCent;                       // overlay: tail data dead now
    int* fI0 = (int*)(tCent + 2048);
    int* fI1 = (int*)(tCent + 3072);
    int* fI2 = (int*)(tCent + 4096);
    int* fI3 = (int*)(tCent + 5120);
    int* fI4 = (int*)(tCent + 6144);

    const int k = *kptr;
    const int M = g_mcount;
    const int nsel = NPTS - k;
    __syncthreads();
    for (int e = t; e < NPTS; e += NTHR) {
        fD0[e] = (e < M) ? g_rech[e] : (double)INFINITY;
        fI0[e] = e;
    }
    __syncthreads();
    for (int k2 = 2; k2 <= NPTS; k2 <<= 1) {
        for (int j2 = k2 >> 1; j2 > 0; j2 >>= 1) {
            for (int i = t; i < NPTS; i += NTHR) {
                int ixj = i ^ j2;
                if (ixj > i) {
                    bool up = ((i & k2) == 0);
                    double a0_ = fD0[i], a1_ = fD0[ixj];
                    if (up ? (a0_ > a1_) : (a0_ < a1_)) {
                        fD0[i] = a1_; fD0[ixj] = a0_;
                        int ti_ = fI0[i]; fI0[i] = fI0[ixj]; fI0[ixj] = ti_;
                    }
                }
            }
            __syncthreads();
        }
    }
    for (int p = t; p < NPTS; p += NTHR) fI1[p] = p;
    __syncthreads();
    for (int r = t; r < nsel; r += NTHR) {
        int rec = fI0[r];
        fI1[g_recj[rec]] = g_reci[rec];   // each killed slot appears exactly once
    }
    __syncthreads();
    int* psrc = fI1; int* pdst = fI2;
    for (int it2 = 0; it2 < 11; ++it2) {          // 2^11 >= max chain depth
        for (int p = t; p < NPTS; p += NTHR) pdst[p] = psrc[psrc[p]];
        __syncthreads();
        int* tp = psrc; psrc = pdst; pdst = tp;
    }
    for (int p = t; p < NPTS; p += NTHR) fI3[p] = (psrc[p] == p) ? 1 : 0;
    __syncthreads();
    int* rsrc = fI3; int* rdst = fI4;
    for (int off = 1; off < NPTS; off <<= 1) {
        for (int p = t; p < NPTS; p += NTHR)
            rdst[p] = rsrc[p] + ((p >= off) ? rsrc[p - off] : 0);
        __syncthreads();
        int* tp = rsrc; rsrc = rdst; rdst = tp;
    }
    for (int p = t; p < NPTS; p += NTHR) {
        int lbl = rsrc[psrc[p]] - 1;              // rank of root, ascending
        out[(size_t)p * k + lbl] = 1.0f;
    }
}

// -------------------------------------------------------------- launch ----
extern "C" void kernel_launch(void* const* d_in, const int* in_sizes, int n_in,
                              void* d_out, int out_size, void* d_ws, size_t ws_size,
                              hipStream_t stream) {
    const float* x    = (const float*)d_in[0];
    const int*   kptr = (const int*)d_in[1];
    float*       out  = (float*)d_out;

    fused<<<NBLK, NTHR, 0, stream>>>(x, kptr, out, out_size);
}